// Round 12
// baseline (401.406 us; speedup 1.0000x reference)
//
#include <hip/hip_runtime.h>

// ---------- constants (problem is fixed-shape) ----------
#define LTOK 36864     // H*W = 192*192
#define DIMC 384
#define NHEADS 6
#define HDIM 64
#define HIDD 768
#define NWIN 12        // windows per side
#define WSZ 16
#define OWS 24
#define KVTOK 576      // 24*24

using bf16x8 = __attribute__((ext_vector_type(8))) short;
using f32x4  = __attribute__((ext_vector_type(4))) float;

__device__ inline unsigned short f2bf(float f) {
  unsigned u = __float_as_uint(f);
  return (unsigned short)((u + 0x7FFFu + ((u >> 16) & 1u)) >> 16);
}
__device__ __forceinline__ unsigned cvt_pk_bf16(float lo, float hi) {
  unsigned r;
  asm volatile("v_cvt_pk_bf16_f32 %0, %1, %2" : "=v"(r) : "v"(lo), "v"(hi));
  return r;
}
__device__ __forceinline__ unsigned short f2bf1(float x) {
  return (unsigned short)(cvt_pk_bf16(x, x) & 0xffffu);
}
__device__ __forceinline__ float fexp2(float x) {
#if __has_builtin(__builtin_amdgcn_exp2f)
  return __builtin_amdgcn_exp2f(x);
#else
  return exp2f(x);
#endif
}

typedef __attribute__((address_space(1))) const unsigned int GAS_U32;
typedef __attribute__((address_space(3))) unsigned int LAS_U32;
__device__ __forceinline__ void gl16(const void* g, void* l) {
  __builtin_amdgcn_global_load_lds((GAS_U32*)g, (LAS_U32*)l, 16, 0, 0);
}

// ---------- fused weight transposes: all 4 convt in one launch ----------
__global__ void prep_kernel(const float* __restrict__ qkv_w, const float* __restrict__ proj_w,
                            const float* __restrict__ fc1_w, const float* __restrict__ fc2_w,
                            unsigned short* __restrict__ wq, unsigned short* __restrict__ wp,
                            unsigned short* __restrict__ w1, unsigned short* __restrict__ w2) {
  int id = blockIdx.x * 256 + threadIdx.x;
  if (id < 442368) {                       // wq[n*384+k] = qkv_w[k*1152+n]
    int n = id / 384, k = id - n * 384;
    wq[id] = f2bf(qkv_w[(size_t)k * 1152 + n]);
  } else if (id < 589824) {                // wp
    int i = id - 442368;
    int n = i / 384, k = i - n * 384;
    wp[i] = f2bf(proj_w[(size_t)k * 384 + n]);
  } else if (id < 884736) {                // w1[n*384+k] = fc1_w[k*768+n]
    int i = id - 589824;
    int n = i / 384, k = i - n * 384;
    w1[i] = f2bf(fc1_w[(size_t)k * 768 + n]);
  } else {                                 // w2[n*768+k] = fc2_w[k*384+n]
    int i = id - 884736;
    int n = i / 768, k = i - n * 768;
    w2[i] = f2bf(fc2_w[(size_t)k * 384 + n]);
  }
}

// ---------- rel-pos bias expand (x8, f32): biasm8[head][q(256)][kt(576)] ----------
__global__ void rpb_expand_kernel(const float* __restrict__ rpb, float* __restrict__ biasm8) {
  int id = blockIdx.x * 256 + threadIdx.x;
  if (id >= NHEADS * 256 * 576) return;
  int head = id / 147456;
  int rem = id - head * 147456;
  int q = rem / 576;
  int kt = rem - q * 576;
  int ty = q >> 4, tx = q & 15;
  int oy = kt / 24, ox = kt - (kt / 24) * 24;
  biasm8[id] = rpb[((ty - oy + 23) * 39 + (tx - ox + 23)) * NHEADS + head] * 8.0f;
}

// ---------- LayerNorm: fp32 in -> bf16 out, one wave per row (384 cols) ----------
__global__ __launch_bounds__(256) void ln_kernel(const float* __restrict__ x,
                                                 const float* __restrict__ g,
                                                 const float* __restrict__ b,
                                                 unsigned short* __restrict__ out) {
  int row = blockIdx.x * 4 + (threadIdx.x >> 6);
  int lane = threadIdx.x & 63;
  const float* xr = x + (size_t)row * DIMC;
  float v[6];
  float s = 0.f, ss = 0.f;
#pragma unroll
  for (int i = 0; i < 6; ++i) {
    v[i] = xr[lane + i * 64];
    s += v[i];
    ss += v[i] * v[i];
  }
#pragma unroll
  for (int off = 32; off; off >>= 1) {
    s += __shfl_xor(s, off);
    ss += __shfl_xor(ss, off);
  }
  float mean = s * (1.f / DIMC);
  float var = ss * (1.f / DIMC) - mean * mean;
  float rstd = rsqrtf(var + 1e-5f);
  unsigned short* outr = out + (size_t)row * DIMC;
#pragma unroll
  for (int i = 0; i < 6; ++i) {
    int c = lane + i * 64;
    outr[c] = f2bf((v[i] - mean) * rstd * g[c] + b[c]);
  }
}

// ---------- bf16 MFMA GEMM: A 3-buf counted-vmcnt LDS, B direct-from-L2 ----------
// B (weights, <=0.9MB) is L2-resident: fragments load straight to VGPRs each iter.
// LDS = A only (24 KB) -> higher co-residency; stage = 2 gl16/iter.
// Counted wait: vmcnt(6) = A(t+1):2 + B(t):4; tail iter uses vmcnt(4).
template <int EPI>
__global__ __launch_bounds__(256) void gemm_bf16(const unsigned short* __restrict__ A,
                                                 const unsigned short* __restrict__ Bt,
                                                 const float* __restrict__ bias,
                                                 const float* __restrict__ resid,
                                                 void* __restrict__ outv,
                                                 int M, int N, int K) {
  __shared__ unsigned short As[3][4096];  // 3 bufs x 8KB (A tile 128x32)
  const int tid = threadIdx.x;
  // bijective XCD swizzle (nwg % 8 == 0 for all our grids)
  int id = blockIdx.y * gridDim.x + blockIdx.x;
  int chunk = (gridDim.x * gridDim.y) >> 3;
  int lid = (id & 7) * chunk + (id >> 3);
  const int m0 = (lid / gridDim.x) * 128;
  const int n0 = (lid % gridDim.x) * 128;
  const int lane = tid & 63;
  const int wave = tid >> 6;
  const int wr = wave >> 1;
  const int wc = wave & 1;
  const int l15 = lane & 15, l4 = lane >> 4;

  f32x4 acc[4][4];
#pragma unroll
  for (int i = 0; i < 4; ++i)
#pragma unroll
    for (int j = 0; j < 4; ++j) acc[i][j] = (f32x4){0.f, 0.f, 0.f, 0.f};

  const int srow = tid >> 2;
  const int scol = (tid & 3) << 3;
  const unsigned short* ga = A + (size_t)(m0 + srow) * K + scol;
  // B fragment source: row n0 + wc*64 + j*16 + l15, k-chunk l4*8
  const unsigned short* gB = Bt + (size_t)(n0 + wc * 64 + l15) * K + l4 * 8;

#define STAGE(buf, k0)                                        \
  do {                                                        \
    unsigned short* lA = As[buf] + wave * 512;                \
    gl16(ga + (k0), lA);                                      \
    gl16(ga + (size_t)64 * K + (k0), lA + 2048);              \
  } while (0)

  const int nt = K >> 5;
  STAGE(0, 0);
  STAGE(1, 32);   // 4 A-loads/thread outstanding

  for (int t = 0; t < nt; ++t) {
    const int cur = t % 3;
    // B fragments for this iteration (L2-resident, compiler-managed waits)
    bf16x8 bfr[4];
#pragma unroll
    for (int j = 0; j < 4; ++j)
      bfr[j] = *(const bf16x8*)(gB + (size_t)(j * 16) * K + t * 32);

    if (t + 1 < nt) {
      asm volatile("s_waitcnt vmcnt(6)" ::: "memory");  // retire A(t); leave A(t+1)+B(t)
    } else {
      asm volatile("s_waitcnt vmcnt(4)" ::: "memory");  // tail: retire all A; leave B(t)
    }
    __builtin_amdgcn_s_barrier();                       // all waves' buf[t] complete

    if (t + 2 < nt) STAGE((t + 2) % 3, (t + 2) * 32);   // overwrites buf read in iter t-1

    const unsigned short* arp = As[cur] + (wr * 64 + l15) * 32 + l4 * 8;
    bf16x8 af[4];
#pragma unroll
    for (int i = 0; i < 4; ++i) af[i] = *(const bf16x8*)(arp + i * 512);
#pragma unroll
    for (int i = 0; i < 4; ++i)
#pragma unroll
      for (int j = 0; j < 4; ++j)
        acc[i][j] = __builtin_amdgcn_mfma_f32_16x16x32_bf16(af[i], bfr[j], acc[i][j], 0, 0, 0);
  }
#undef STAGE
  asm volatile("s_waitcnt vmcnt(0)" ::: "memory");

#pragma unroll
  for (int j = 0; j < 4; ++j) {
    int gcol = n0 + wc * 64 + j * 16 + l15;
    float bv = bias[gcol];
#pragma unroll
    for (int i = 0; i < 4; ++i) {
#pragma unroll
      for (int r = 0; r < 4; ++r) {
        int grow = m0 + wr * 64 + i * 16 + l4 * 4 + r;
        float v = acc[i][j][r] + bv;
        size_t idx = (size_t)grow * N + gcol;
        if (EPI == 0) {
          ((unsigned short*)outv)[idx] = f2bf(v);
        } else if (EPI == 1) {
          ((float*)outv)[idx] = resid[idx] + v;
        } else {
          float gv = 0.5f * v * (1.f + erff(v * 0.70710678118654752f));
          ((unsigned short*)outv)[idx] = f2bf(gv);
        }
      }
    }
  }
}

// ---------- MFMA flash attention ----------
// Round-11 structure (dbuf K/V^T, 1 barrier/tile) + bias register double-prefetch:
// bnext[4][2] loaded a FULL tile ahead; kk=0 MFMAs consume bnext as C directly
// (no copies), then bnext reloads for the next tile while kk=1/softmax/PV run.
__global__ __launch_bounds__(256, 3) void attn_kernel(const unsigned short* __restrict__ qkv,
                                                      const float* __restrict__ biasm8,
                                                      unsigned short* __restrict__ att) {
  __shared__ unsigned short ks[2][64][72];   // K tile [kt][d], dbuf
  __shared__ unsigned short vts[2][64][72];  // V^T tile [d][kt], dbuf
  __shared__ unsigned short pt[4][32][40];   // per-wave P kk-half
  int bid = blockIdx.x;                       // 0..1727
  int lid = (bid & 7) * 216 + (bid >> 3);     // bijective XCD swizzle (1728 = 8*216)
  const int hw = lid >> 1;
  const int qh = lid & 1;
  const int win = hw / NHEADS;
  const int head = hw - win * NHEADS;
  const int wy = win / NWIN, wx = win - (win / NWIN) * NWIN;
  const int tid = threadIdx.x;
  const int w = tid >> 6, lane = tid & 63;
  const int l15 = lane & 15, l4 = lane >> 4;
  const float SC02 = 0.125f * 1.44269504f;
  const float C0 = -8.f * 1.44269504f;

  const int qrow0 = qh * 128 + w * 32;

  bf16x8 qf[2][2];
#pragma unroll
  for (int jq = 0; jq < 2; ++jq) {
    int q = qrow0 + jq * 16 + l15;
    int gy = wy * WSZ + (q >> 4), gx = wx * WSZ + (q & 15);
    const unsigned short* qp = qkv + (size_t)(gy * 192 + gx) * 1152 + head * HDIM + l4 * 8;
    qf[jq][0] = *(const bf16x8*)qp;
    qf[jq][1] = *(const bf16x8*)(qp + 32);
  }

  const float* bias_base = biasm8 + (size_t)head * 147456 + (size_t)(qrow0 + l15) * 576 + l4 * 4;

#define KS_W(buf, k0v, k1v)                          \
  do {                                               \
    *(uint4*)&ks[buf][lane][w * 16] = (k0v);         \
    *(uint4*)&ks[buf][lane][w * 16 + 8] = (k1v);     \
  } while (0)
#define VTS_W(buf, v0v, v1v)                                           \
  do {                                                                 \
    const unsigned short* vv = (const unsigned short*)&(v0v);          \
    _Pragma("unroll") for (int j = 0; j < 8; ++j)                      \
        vts[buf][w * 16 + j][lane] = vv[j];                            \
    vv = (const unsigned short*)&(v1v);                                \
    _Pragma("unroll") for (int j = 0; j < 8; ++j)                      \
        vts[buf][w * 16 + 8 + j][lane] = vv[j];                        \
  } while (0)

  {
    int kt = lane;
    int oy = kt / OWS, ox = kt - (kt / OWS) * OWS;
    int gy = wy * WSZ + oy - 4, gx = wx * WSZ + ox - 4;
    uint4 k0 = {0,0,0,0}, k1 = {0,0,0,0}, v0 = {0,0,0,0}, v1 = {0,0,0,0};
    if ((unsigned)gy < 192u && (unsigned)gx < 192u) {
      const unsigned short* gp = qkv + (size_t)(gy * 192 + gx) * 1152 + DIMC + head * HDIM + w * 16;
      k0 = *(const uint4*)gp;         k1 = *(const uint4*)(gp + 8);
      v0 = *(const uint4*)(gp + 384); v1 = *(const uint4*)(gp + 392);
    }
    KS_W(0, k0, k1);
    VTS_W(0, v0, v1);
  }

  // bias tile 0 prefetch (full cover: issued before the staging barrier)
  f32x4 bnext[4][2];
#pragma unroll
  for (int i = 0; i < 4; ++i)
#pragma unroll
    for (int j2 = 0; j2 < 2; ++j2)
      bnext[i][j2] = *(const f32x4*)(bias_base + j2 * (16 * 576) + i * 16);

  __syncthreads();

  f32x4 oacc[2][4];
#pragma unroll
  for (int i = 0; i < 2; ++i)
#pragma unroll
    for (int j = 0; j < 4; ++j) oacc[i][j] = (f32x4){0.f, 0.f, 0.f, 0.f};
  float plsum[2] = {0.f, 0.f};

  for (int kb = 0; kb < 9; ++kb) {
    const int cur = kb & 1;
    const bool have = kb < 8;
    // T14: issue K/V prefetch loads for tile kb+1 (consumed at tile end)
    uint4 pk0 = {0,0,0,0}, pk1 = {0,0,0,0}, pv0 = {0,0,0,0}, pv1 = {0,0,0,0};
    if (have) {
      int kt = (kb + 1) * 64 + lane;
      int oy = kt / OWS, ox = kt - (kt / OWS) * OWS;
      int gy = wy * WSZ + oy - 4, gx = wx * WSZ + ox - 4;
      if ((unsigned)gy < 192u && (unsigned)gx < 192u) {
        const unsigned short* gp = qkv + (size_t)(gy * 192 + gx) * 1152 + DIMC + head * HDIM + w * 16;
        pk0 = *(const uint4*)gp;         pk1 = *(const uint4*)(gp + 8);
        pv0 = *(const uint4*)(gp + 384); pv1 = *(const uint4*)(gp + 392);
      }
    }

    // ----- QK^T kk=0: C-init = bnext (bias), consumed here -----
    f32x4 sacc[4][2];
    {
      bf16x8 kf[4];
#pragma unroll
      for (int i = 0; i < 4; ++i)
        kf[i] = *(const bf16x8*)&ks[cur][i * 16 + l15][l4 * 8];
      __builtin_amdgcn_s_setprio(1);
#pragma unroll
      for (int i = 0; i < 4; ++i)
#pragma unroll
        for (int j2 = 0; j2 < 2; ++j2)
          sacc[i][j2] = __builtin_amdgcn_mfma_f32_16x16x32_bf16(kf[i], qf[j2][0], bnext[i][j2], 0, 0, 0);
      __builtin_amdgcn_s_setprio(0);
    }
    // reload bnext for tile kb+1 (bnext regs now free; ~full tile of cover)
    if (have) {
      const float* bp = bias_base + (kb + 1) * 64;
#pragma unroll
      for (int i = 0; i < 4; ++i)
#pragma unroll
        for (int j2 = 0; j2 < 2; ++j2)
          bnext[i][j2] = *(const f32x4*)(bp + j2 * (16 * 576) + i * 16);
    }
    // ----- QK^T kk=1 -----
    {
      bf16x8 kf[4];
#pragma unroll
      for (int i = 0; i < 4; ++i)
        kf[i] = *(const bf16x8*)&ks[cur][i * 16 + l15][32 + l4 * 8];
      __builtin_amdgcn_s_setprio(1);
#pragma unroll
      for (int i = 0; i < 4; ++i)
#pragma unroll
        for (int j2 = 0; j2 < 2; ++j2)
          sacc[i][j2] = __builtin_amdgcn_mfma_f32_16x16x32_bf16(kf[i], qf[j2][1], sacc[i][j2], 0, 0, 0);
      __builtin_amdgcn_s_setprio(0);
    }

    // ----- P = exp2(s*SC02 + C0) (static max), per-lane partial sums -----
#pragma unroll
    for (int i = 0; i < 4; ++i)
#pragma unroll
      for (int j2 = 0; j2 < 2; ++j2)
#pragma unroll
        for (int r = 0; r < 4; ++r) {
          float p = fexp2(fmaf(sacc[i][j2][r], SC02, C0));
          sacc[i][j2][r] = p;
          plsum[j2] += p;
        }

    // ----- PV per kk-half: pack P via cvt_pk, per-wave LDS round-trip -----
#pragma unroll
    for (int kk = 0; kk < 2; ++kk) {
#pragma unroll
      for (int i2 = 0; i2 < 2; ++i2)
#pragma unroll
        for (int j2 = 0; j2 < 2; ++j2) {
          int i = kk * 2 + i2;
          uint2 pk;
          pk.x = cvt_pk_bf16(sacc[i][j2][0], sacc[i][j2][1]);
          pk.y = cvt_pk_bf16(sacc[i][j2][2], sacc[i][j2][3]);
          *(uint2*)&pt[w][j2 * 16 + l15][i2 * 16 + l4 * 4] = pk;
        }
      bf16x8 pf[2], vf[4];
#pragma unroll
      for (int j2 = 0; j2 < 2; ++j2)
        pf[j2] = *(const bf16x8*)&pt[w][j2 * 16 + l15][l4 * 8];
#pragma unroll
      for (int jd = 0; jd < 4; ++jd)
        vf[jd] = *(const bf16x8*)&vts[cur][jd * 16 + l15][kk * 32 + l4 * 8];
      __builtin_amdgcn_s_setprio(1);
#pragma unroll
      for (int j2 = 0; j2 < 2; ++j2)
#pragma unroll
        for (int jd = 0; jd < 4; ++jd)
          oacc[j2][jd] = __builtin_amdgcn_mfma_f32_16x16x32_bf16(pf[j2], vf[jd], oacc[j2][jd], 0, 0, 0);
      __builtin_amdgcn_s_setprio(0);
    }

    // ----- write staged tile kb+1 into buf^1 -----
    if (have) {
      KS_W(cur ^ 1, pk0, pk1);
      VTS_W(cur ^ 1, pv0, pv1);
    }
    __syncthreads();  // single barrier per tile
  }
#undef KS_W
#undef VTS_W

  float invl[2];
#pragma unroll
  for (int j2 = 0; j2 < 2; ++j2) {
    plsum[j2] += __shfl_xor(plsum[j2], 16);
    plsum[j2] += __shfl_xor(plsum[j2], 32);
    invl[j2] = 1.f / plsum[j2];
  }

#pragma unroll
  for (int j2 = 0; j2 < 2; ++j2) {
#pragma unroll
    for (int r = 0; r < 4; ++r) {
      float il = __shfl(invl[j2], l4 * 4 + r);
      int q = qrow0 + j2 * 16 + l4 * 4 + r;
      int gy = wy * WSZ + (q >> 4), gx = wx * WSZ + (q & 15);
      unsigned short* op = att + (size_t)(gy * 192 + gx) * DIMC + head * HDIM + l15;
#pragma unroll
      for (int jd = 0; jd < 4; ++jd) op[jd * 16] = f2bf1(oacc[j2][jd][r] * il);
    }
  }
}

// ---------- launch ----------
extern "C" void kernel_launch(void* const* d_in, const int* in_sizes, int n_in,
                              void* d_out, int out_size, void* d_ws, size_t ws_size,
                              hipStream_t stream) {
  const float* x      = (const float*)d_in[0];
  const float* n1g    = (const float*)d_in[1];
  const float* n1b    = (const float*)d_in[2];
  const float* qkv_w  = (const float*)d_in[3];
  const float* qkv_b  = (const float*)d_in[4];
  const float* rpb    = (const float*)d_in[5];
  const float* proj_w = (const float*)d_in[6];
  const float* proj_b = (const float*)d_in[7];
  const float* n2g    = (const float*)d_in[8];
  const float* n2b    = (const float*)d_in[9];
  const float* fc1_w  = (const float*)d_in[10];
  const float* fc1_b  = (const float*)d_in[11];
  const float* fc2_w  = (const float*)d_in[12];
  const float* fc2_b  = (const float*)d_in[13];
  float* out = (float*)d_out;

  char* ws = (char*)d_ws;
  unsigned short* xn   = (unsigned short*)ws;                           // L*384 bf16; reused as biasm8 (f32) during attn
  unsigned short* qkvb = (unsigned short*)(ws + 28311552);              // L*1152 bf16, reused as h1
  unsigned short* att  = (unsigned short*)(ws + 28311552 + 84934656);   // L*384 bf16
  unsigned short* wq   = (unsigned short*)(ws + 141557760);             // 1152*384
  unsigned short* wp   = wq + 1152 * 384;                               // 384*384
  unsigned short* w1   = wp + 384 * 384;                                // 768*384
  unsigned short* w2   = w1 + 768 * 384;                                // 384*768
  float* biasm8 = (float*)ws;  // 884736 f32 = 3.54 MB; valid between qkv GEMM and LN2

  // fused weight transposes (1179648 elems)
  prep_kernel<<<4608, 256, 0, stream>>>(qkv_w, proj_w, fc1_w, fc2_w, wq, wp, w1, w2);

  // LN1
  ln_kernel<<<LTOK / 4, 256, 0, stream>>>(x, n1g, n1b, xn);
  // qkv = xn @ qkv_w + b
  gemm_bf16<0><<<dim3(1152 / 128, LTOK / 128), 256, 0, stream>>>(xn, wq, qkv_b, nullptr, qkvb,
                                                                 LTOK, 1152, DIMC);
  // bias matrix expand (f32, x8) into xn region
  rpb_expand_kernel<<<(NHEADS * 256 * 576 + 255) / 256, 256, 0, stream>>>(rpb, biasm8);
  // attention
  attn_kernel<<<dim3(NHEADS * 144 * 2), 256, 0, stream>>>(qkvb, biasm8, att);
  // xa = x + att @ proj_w + b
  gemm_bf16<1><<<dim3(DIMC / 128, LTOK / 128), 256, 0, stream>>>(att, wp, proj_b, x, out,
                                                                 LTOK, DIMC, DIMC);
  // LN2
  ln_kernel<<<LTOK / 4, 256, 0, stream>>>(out, n2g, n2b, xn);
  // h1 = gelu(xn @ fc1_w + b)
  gemm_bf16<2><<<dim3(HIDD / 128, LTOK / 128), 256, 0, stream>>>(xn, w1, fc1_b, nullptr, qkvb,
                                                                 LTOK, HIDD, DIMC);
  // out = xa + h1 @ fc2_w + b
  gemm_bf16<1><<<dim3(DIMC / 128, LTOK / 128), 256, 0, stream>>>(qkvb, w2, fc2_b, out, out,
                                                                 LTOK, DIMC, HIDD);
}

// Round 13
// 339.191 us; speedup vs baseline: 1.1834x; 1.1834x over previous
//
#include <hip/hip_runtime.h>

// ---------- constants (problem is fixed-shape) ----------
#define LTOK 36864     // H*W = 192*192
#define DIMC 384
#define NHEADS 6
#define HDIM 64
#define HIDD 768
#define NWIN 12        // windows per side
#define WSZ 16
#define OWS 24
#define KVTOK 576      // 24*24

using bf16x8 = __attribute__((ext_vector_type(8))) short;
using f32x4  = __attribute__((ext_vector_type(4))) float;

__device__ inline unsigned short f2bf(float f) {
  unsigned u = __float_as_uint(f);
  return (unsigned short)((u + 0x7FFFu + ((u >> 16) & 1u)) >> 16);
}
__device__ __forceinline__ unsigned cvt_pk_bf16(float lo, float hi) {
  unsigned r;
  asm volatile("v_cvt_pk_bf16_f32 %0, %1, %2" : "=v"(r) : "v"(lo), "v"(hi));
  return r;
}
__device__ __forceinline__ unsigned short f2bf1(float x) {
  return (unsigned short)(cvt_pk_bf16(x, x) & 0xffffu);
}
__device__ __forceinline__ float fexp2(float x) {
#if __has_builtin(__builtin_amdgcn_exp2f)
  return __builtin_amdgcn_exp2f(x);
#else
  return exp2f(x);
#endif
}

typedef __attribute__((address_space(1))) const unsigned int GAS_U32;
typedef __attribute__((address_space(3))) unsigned int LAS_U32;
__device__ __forceinline__ void gl16(const void* g, void* l) {
  __builtin_amdgcn_global_load_lds((GAS_U32*)g, (LAS_U32*)l, 16, 0, 0);
}

// ---------- fused weight transposes: all 4 convt in one launch ----------
__global__ void prep_kernel(const float* __restrict__ qkv_w, const float* __restrict__ proj_w,
                            const float* __restrict__ fc1_w, const float* __restrict__ fc2_w,
                            unsigned short* __restrict__ wq, unsigned short* __restrict__ wp,
                            unsigned short* __restrict__ w1, unsigned short* __restrict__ w2) {
  int id = blockIdx.x * 256 + threadIdx.x;
  if (id < 442368) {                       // wq[n*384+k] = qkv_w[k*1152+n]
    int n = id / 384, k = id - n * 384;
    wq[id] = f2bf(qkv_w[(size_t)k * 1152 + n]);
  } else if (id < 589824) {                // wp
    int i = id - 442368;
    int n = i / 384, k = i - n * 384;
    wp[i] = f2bf(proj_w[(size_t)k * 384 + n]);
  } else if (id < 884736) {                // w1[n*384+k] = fc1_w[k*768+n]
    int i = id - 589824;
    int n = i / 384, k = i - n * 384;
    w1[i] = f2bf(fc1_w[(size_t)k * 768 + n]);
  } else {                                 // w2[n*768+k] = fc2_w[k*384+n]
    int i = id - 884736;
    int n = i / 768, k = i - n * 768;
    w2[i] = f2bf(fc2_w[(size_t)k * 384 + n]);
  }
}

// ---------- rel-pos bias expand (x8, f32): biasm8[head][q(256)][kt(576)] ----------
__global__ void rpb_expand_kernel(const float* __restrict__ rpb, float* __restrict__ biasm8) {
  int id = blockIdx.x * 256 + threadIdx.x;
  if (id >= NHEADS * 256 * 576) return;
  int head = id / 147456;
  int rem = id - head * 147456;
  int q = rem / 576;
  int kt = rem - q * 576;
  int ty = q >> 4, tx = q & 15;
  int oy = kt / 24, ox = kt - (kt / 24) * 24;
  biasm8[id] = rpb[((ty - oy + 23) * 39 + (tx - ox + 23)) * NHEADS + head] * 8.0f;
}

// ---------- LayerNorm: fp32 in -> bf16 out, one wave per row (384 cols) ----------
__global__ __launch_bounds__(256) void ln_kernel(const float* __restrict__ x,
                                                 const float* __restrict__ g,
                                                 const float* __restrict__ b,
                                                 unsigned short* __restrict__ out) {
  int row = blockIdx.x * 4 + (threadIdx.x >> 6);
  int lane = threadIdx.x & 63;
  const float* xr = x + (size_t)row * DIMC;
  float v[6];
  float s = 0.f, ss = 0.f;
#pragma unroll
  for (int i = 0; i < 6; ++i) {
    v[i] = xr[lane + i * 64];
    s += v[i];
    ss += v[i] * v[i];
  }
#pragma unroll
  for (int off = 32; off; off >>= 1) {
    s += __shfl_xor(s, off);
    ss += __shfl_xor(ss, off);
  }
  float mean = s * (1.f / DIMC);
  float var = ss * (1.f / DIMC) - mean * mean;
  float rstd = rsqrtf(var + 1e-5f);
  unsigned short* outr = out + (size_t)row * DIMC;
#pragma unroll
  for (int i = 0; i < 6; ++i) {
    int c = lane + i * 64;
    outr[c] = f2bf((v[i] - mean) * rstd * g[c] + b[c]);
  }
}

// ---------- bf16 MFMA GEMM: 256x128 tile, 8 waves, 3-buf counted-vmcnt ----------
// Per iter: one vmcnt + one barrier covers 2x the FLOPs of the 128x128 version.
// Staging = 3 gl16/thread (A:2, B:1); steady wait vmcnt(3); final iter vmcnt(0).
// LDS = 72 KB -> 2 blocks/CU = 4 waves/SIMD.
template <int EPI>
__global__ __launch_bounds__(512) void gemm_bf16(const unsigned short* __restrict__ A,
                                                 const unsigned short* __restrict__ Bt,
                                                 const float* __restrict__ bias,
                                                 const float* __restrict__ resid,
                                                 void* __restrict__ outv,
                                                 int M, int N, int K) {
  __shared__ unsigned short As[3][8192];  // 3 bufs x 16KB (A tile 256x32)
  __shared__ unsigned short Bs[3][4096];  // 3 bufs x 8KB  (B tile 128x32)
  const int tid = threadIdx.x;
  // bijective XCD swizzle (nwg % 8 == 0 for all our grids)
  int id = blockIdx.y * gridDim.x + blockIdx.x;
  int chunk = (gridDim.x * gridDim.y) >> 3;
  int lid = (id & 7) * chunk + (id >> 3);
  const int m0 = (lid / gridDim.x) * 256;
  const int n0 = (lid % gridDim.x) * 128;
  const int lane = tid & 63;
  const int wave = tid >> 6;
  const int wr = wave >> 1;   // 0..3 (64-row slab)
  const int wc = wave & 1;    // 0..1 (64-col slab)
  const int l15 = lane & 15, l4 = lane >> 4;

  f32x4 acc[4][4];
#pragma unroll
  for (int i = 0; i < 4; ++i)
#pragma unroll
    for (int j = 0; j < 4; ++j) acc[i][j] = (f32x4){0.f, 0.f, 0.f, 0.f};

  // staging: thread t covers chunk t (16B): row = t>>2, col = (t&3)*8
  const int srow = tid >> 2;              // 0..127
  const int scol = (tid & 3) << 3;
  const unsigned short* ga = A + (size_t)(m0 + srow) * K + scol;
  const unsigned short* gb = Bt + (size_t)(n0 + srow) * K + scol;

#define STAGE(buf, k0)                                        \
  do {                                                        \
    unsigned short* lA = As[buf] + wave * 512;                \
    unsigned short* lB = Bs[buf] + wave * 512;                \
    gl16(ga + (k0), lA);                                      \
    gl16(ga + (size_t)128 * K + (k0), lA + 4096);             \
    gl16(gb + (k0), lB);                                      \
  } while (0)

  const int nt = K >> 5;
  STAGE(0, 0);
  STAGE(1, 32);   // 6 loads/thread outstanding

  for (int t = 0; t < nt; ++t) {
    const int cur = t % 3;
    if (t + 1 < nt) {
      asm volatile("s_waitcnt vmcnt(3)" ::: "memory");  // stage t retired (in-order)
    } else {
      asm volatile("s_waitcnt vmcnt(0)" ::: "memory");  // tail: only stage t outstanding
    }
    __builtin_amdgcn_s_barrier();                       // all waves' buf[t] complete

    if (t + 2 < nt) STAGE((t + 2) % 3, (t + 2) * 32);   // overwrites buf read in iter t-1

    const unsigned short* arp = As[cur] + (wr * 64 + l15) * 32 + l4 * 8;
    const unsigned short* brp = Bs[cur] + (wc * 64 + l15) * 32 + l4 * 8;
    bf16x8 af[4], bfr[4];
#pragma unroll
    for (int i = 0; i < 4; ++i) af[i] = *(const bf16x8*)(arp + i * 512);
#pragma unroll
    for (int j = 0; j < 4; ++j) bfr[j] = *(const bf16x8*)(brp + j * 512);
#pragma unroll
    for (int i = 0; i < 4; ++i)
#pragma unroll
      for (int j = 0; j < 4; ++j)
        acc[i][j] = __builtin_amdgcn_mfma_f32_16x16x32_bf16(af[i], bfr[j], acc[i][j], 0, 0, 0);
  }
#undef STAGE

#pragma unroll
  for (int j = 0; j < 4; ++j) {
    int gcol = n0 + wc * 64 + j * 16 + l15;
    float bv = bias[gcol];
#pragma unroll
    for (int i = 0; i < 4; ++i) {
#pragma unroll
      for (int r = 0; r < 4; ++r) {
        int grow = m0 + wr * 64 + i * 16 + l4 * 4 + r;
        float v = acc[i][j][r] + bv;
        size_t idx = (size_t)grow * N + gcol;
        if (EPI == 0) {
          ((unsigned short*)outv)[idx] = f2bf(v);
        } else if (EPI == 1) {
          ((float*)outv)[idx] = resid[idx] + v;
        } else {
          float gv = 0.5f * v * (1.f + erff(v * 0.70710678118654752f));
          ((unsigned short*)outv)[idx] = f2bf(gv);
        }
      }
    }
  }
}

// ---------- MFMA flash attention (round-11 best: dbuf K/V^T, 1 barrier/tile) ----------
__global__ __launch_bounds__(256, 3) void attn_kernel(const unsigned short* __restrict__ qkv,
                                                      const float* __restrict__ biasm8,
                                                      unsigned short* __restrict__ att) {
  __shared__ unsigned short ks[2][64][72];   // K tile [kt][d], dbuf
  __shared__ unsigned short vts[2][64][72];  // V^T tile [d][kt], dbuf
  __shared__ unsigned short pt[4][32][40];   // per-wave P kk-half
  int bid = blockIdx.x;                       // 0..1727
  int lid = (bid & 7) * 216 + (bid >> 3);     // bijective XCD swizzle (1728 = 8*216)
  const int hw = lid >> 1;
  const int qh = lid & 1;
  const int win = hw / NHEADS;
  const int head = hw - win * NHEADS;
  const int wy = win / NWIN, wx = win - (win / NWIN) * NWIN;
  const int tid = threadIdx.x;
  const int w = tid >> 6, lane = tid & 63;
  const int l15 = lane & 15, l4 = lane >> 4;
  const float SC02 = 0.125f * 1.44269504f;
  const float C0 = -8.f * 1.44269504f;

  const int qrow0 = qh * 128 + w * 32;

  bf16x8 qf[2][2];
#pragma unroll
  for (int jq = 0; jq < 2; ++jq) {
    int q = qrow0 + jq * 16 + l15;
    int gy = wy * WSZ + (q >> 4), gx = wx * WSZ + (q & 15);
    const unsigned short* qp = qkv + (size_t)(gy * 192 + gx) * 1152 + head * HDIM + l4 * 8;
    qf[jq][0] = *(const bf16x8*)qp;
    qf[jq][1] = *(const bf16x8*)(qp + 32);
  }

  const float* bias_base = biasm8 + (size_t)head * 147456 + (size_t)(qrow0 + l15) * 576 + l4 * 4;

#define KS_W(buf, k0v, k1v)                          \
  do {                                               \
    *(uint4*)&ks[buf][lane][w * 16] = (k0v);         \
    *(uint4*)&ks[buf][lane][w * 16 + 8] = (k1v);     \
  } while (0)
#define VTS_W(buf, v0v, v1v)                                           \
  do {                                                                 \
    const unsigned short* vv = (const unsigned short*)&(v0v);          \
    _Pragma("unroll") for (int j = 0; j < 8; ++j)                      \
        vts[buf][w * 16 + j][lane] = vv[j];                            \
    vv = (const unsigned short*)&(v1v);                                \
    _Pragma("unroll") for (int j = 0; j < 8; ++j)                      \
        vts[buf][w * 16 + 8 + j][lane] = vv[j];                        \
  } while (0)

  {
    int kt = lane;
    int oy = kt / OWS, ox = kt - (kt / OWS) * OWS;
    int gy = wy * WSZ + oy - 4, gx = wx * WSZ + ox - 4;
    uint4 k0 = {0,0,0,0}, k1 = {0,0,0,0}, v0 = {0,0,0,0}, v1 = {0,0,0,0};
    if ((unsigned)gy < 192u && (unsigned)gx < 192u) {
      const unsigned short* gp = qkv + (size_t)(gy * 192 + gx) * 1152 + DIMC + head * HDIM + w * 16;
      k0 = *(const uint4*)gp;         k1 = *(const uint4*)(gp + 8);
      v0 = *(const uint4*)(gp + 384); v1 = *(const uint4*)(gp + 392);
    }
    KS_W(0, k0, k1);
    VTS_W(0, v0, v1);
  }

  f32x4 sacc[4][2];
#pragma unroll
  for (int i = 0; i < 4; ++i)
#pragma unroll
    for (int j2 = 0; j2 < 2; ++j2)
      sacc[i][j2] = *(const f32x4*)(bias_base + j2 * (16 * 576) + i * 16);

  __syncthreads();

  f32x4 oacc[2][4];
#pragma unroll
  for (int i = 0; i < 2; ++i)
#pragma unroll
    for (int j = 0; j < 4; ++j) oacc[i][j] = (f32x4){0.f, 0.f, 0.f, 0.f};
  float plsum[2] = {0.f, 0.f};

  for (int kb = 0; kb < 9; ++kb) {
    const int cur = kb & 1;
    const bool have = kb < 8;
    uint4 pk0 = {0,0,0,0}, pk1 = {0,0,0,0}, pv0 = {0,0,0,0}, pv1 = {0,0,0,0};
    if (have) {
      int kt = (kb + 1) * 64 + lane;
      int oy = kt / OWS, ox = kt - (kt / OWS) * OWS;
      int gy = wy * WSZ + oy - 4, gx = wx * WSZ + ox - 4;
      if ((unsigned)gy < 192u && (unsigned)gx < 192u) {
        const unsigned short* gp = qkv + (size_t)(gy * 192 + gx) * 1152 + DIMC + head * HDIM + w * 16;
        pk0 = *(const uint4*)gp;         pk1 = *(const uint4*)(gp + 8);
        pv0 = *(const uint4*)(gp + 384); pv1 = *(const uint4*)(gp + 392);
      }
    }

#pragma unroll
    for (int kk = 0; kk < 2; ++kk) {
      bf16x8 kf[4];
#pragma unroll
      for (int i = 0; i < 4; ++i)
        kf[i] = *(const bf16x8*)&ks[cur][i * 16 + l15][kk * 32 + l4 * 8];
      __builtin_amdgcn_s_setprio(1);
#pragma unroll
      for (int i = 0; i < 4; ++i)
#pragma unroll
        for (int j2 = 0; j2 < 2; ++j2)
          sacc[i][j2] = __builtin_amdgcn_mfma_f32_16x16x32_bf16(kf[i], qf[j2][kk], sacc[i][j2], 0, 0, 0);
      __builtin_amdgcn_s_setprio(0);
    }

#pragma unroll
    for (int i = 0; i < 4; ++i)
#pragma unroll
      for (int j2 = 0; j2 < 2; ++j2)
#pragma unroll
        for (int r = 0; r < 4; ++r) {
          float p = fexp2(fmaf(sacc[i][j2][r], SC02, C0));
          sacc[i][j2][r] = p;
          plsum[j2] += p;
        }

#pragma unroll
    for (int kk = 0; kk < 2; ++kk) {
#pragma unroll
      for (int i2 = 0; i2 < 2; ++i2)
#pragma unroll
        for (int j2 = 0; j2 < 2; ++j2) {
          int i = kk * 2 + i2;
          uint2 pk;
          pk.x = cvt_pk_bf16(sacc[i][j2][0], sacc[i][j2][1]);
          pk.y = cvt_pk_bf16(sacc[i][j2][2], sacc[i][j2][3]);
          *(uint2*)&pt[w][j2 * 16 + l15][i2 * 16 + l4 * 4] = pk;
        }
      bf16x8 pf[2], vf[4];
#pragma unroll
      for (int j2 = 0; j2 < 2; ++j2)
        pf[j2] = *(const bf16x8*)&pt[w][j2 * 16 + l15][l4 * 8];
#pragma unroll
      for (int jd = 0; jd < 4; ++jd)
        vf[jd] = *(const bf16x8*)&vts[cur][jd * 16 + l15][kk * 32 + l4 * 8];
      __builtin_amdgcn_s_setprio(1);
#pragma unroll
      for (int j2 = 0; j2 < 2; ++j2)
#pragma unroll
        for (int jd = 0; jd < 4; ++jd)
          oacc[j2][jd] = __builtin_amdgcn_mfma_f32_16x16x32_bf16(pf[j2], vf[jd], oacc[j2][jd], 0, 0, 0);
      __builtin_amdgcn_s_setprio(0);
    }

    if (have) {
      KS_W(cur ^ 1, pk0, pk1);
      VTS_W(cur ^ 1, pv0, pv1);
      const float* bp = bias_base + (kb + 1) * 64;
#pragma unroll
      for (int i = 0; i < 4; ++i)
#pragma unroll
        for (int j2 = 0; j2 < 2; ++j2)
          sacc[i][j2] = *(const f32x4*)(bp + j2 * (16 * 576) + i * 16);
    }
    __syncthreads();
  }
#undef KS_W
#undef VTS_W

  float invl[2];
#pragma unroll
  for (int j2 = 0; j2 < 2; ++j2) {
    plsum[j2] += __shfl_xor(plsum[j2], 16);
    plsum[j2] += __shfl_xor(plsum[j2], 32);
    invl[j2] = 1.f / plsum[j2];
  }

#pragma unroll
  for (int j2 = 0; j2 < 2; ++j2) {
#pragma unroll
    for (int r = 0; r < 4; ++r) {
      float il = __shfl(invl[j2], l4 * 4 + r);
      int q = qrow0 + j2 * 16 + l4 * 4 + r;
      int gy = wy * WSZ + (q >> 4), gx = wx * WSZ + (q & 15);
      unsigned short* op = att + (size_t)(gy * 192 + gx) * DIMC + head * HDIM + l15;
#pragma unroll
      for (int jd = 0; jd < 4; ++jd) op[jd * 16] = f2bf1(oacc[j2][jd][r] * il);
    }
  }
}

// ---------- launch ----------
extern "C" void kernel_launch(void* const* d_in, const int* in_sizes, int n_in,
                              void* d_out, int out_size, void* d_ws, size_t ws_size,
                              hipStream_t stream) {
  const float* x      = (const float*)d_in[0];
  const float* n1g    = (const float*)d_in[1];
  const float* n1b    = (const float*)d_in[2];
  const float* qkv_w  = (const float*)d_in[3];
  const float* qkv_b  = (const float*)d_in[4];
  const float* rpb    = (const float*)d_in[5];
  const float* proj_w = (const float*)d_in[6];
  const float* proj_b = (const float*)d_in[7];
  const float* n2g    = (const float*)d_in[8];
  const float* n2b    = (const float*)d_in[9];
  const float* fc1_w  = (const float*)d_in[10];
  const float* fc1_b  = (const float*)d_in[11];
  const float* fc2_w  = (const float*)d_in[12];
  const float* fc2_b  = (const float*)d_in[13];
  float* out = (float*)d_out;

  char* ws = (char*)d_ws;
  unsigned short* xn   = (unsigned short*)ws;                           // L*384 bf16; reused as biasm8 (f32) during attn
  unsigned short* qkvb = (unsigned short*)(ws + 28311552);              // L*1152 bf16, reused as h1
  unsigned short* att  = (unsigned short*)(ws + 28311552 + 84934656);   // L*384 bf16
  unsigned short* wq   = (unsigned short*)(ws + 141557760);             // 1152*384
  unsigned short* wp   = wq + 1152 * 384;                               // 384*384
  unsigned short* w1   = wp + 384 * 384;                                // 768*384
  unsigned short* w2   = w1 + 768 * 384;                                // 384*768
  float* biasm8 = (float*)ws;  // 884736 f32 = 3.54 MB; valid between qkv GEMM and LN2

  // fused weight transposes (1179648 elems)
  prep_kernel<<<4608, 256, 0, stream>>>(qkv_w, proj_w, fc1_w, fc2_w, wq, wp, w1, w2);

  // LN1
  ln_kernel<<<LTOK / 4, 256, 0, stream>>>(x, n1g, n1b, xn);
  // qkv = xn @ qkv_w + b   (grid 9 x 144 = 1296)
  gemm_bf16<0><<<dim3(1152 / 128, LTOK / 256), 512, 0, stream>>>(xn, wq, qkv_b, nullptr, qkvb,
                                                                 LTOK, 1152, DIMC);
  // bias matrix expand (f32, x8) into xn region
  rpb_expand_kernel<<<(NHEADS * 256 * 576 + 255) / 256, 256, 0, stream>>>(rpb, biasm8);
  // attention
  attn_kernel<<<dim3(NHEADS * 144 * 2), 256, 0, stream>>>(qkvb, biasm8, att);
  // xa = x + att @ proj_w + b   (grid 3 x 144 = 432)
  gemm_bf16<1><<<dim3(DIMC / 128, LTOK / 256), 512, 0, stream>>>(att, wp, proj_b, x, out,
                                                                 LTOK, DIMC, DIMC);
  // LN2
  ln_kernel<<<LTOK / 4, 256, 0, stream>>>(out, n2g, n2b, xn);
  // h1 = gelu(xn @ fc1_w + b)  (grid 6 x 144 = 864)
  gemm_bf16<2><<<dim3(HIDD / 128, LTOK / 256), 512, 0, stream>>>(xn, w1, fc1_b, nullptr, qkvb,
                                                                 LTOK, HIDD, DIMC);
  // out = xa + h1 @ fc2_w + b  (grid 3 x 144 = 432)
  gemm_bf16<1><<<dim3(DIMC / 128, LTOK / 256), 512, 0, stream>>>(qkvb, w2, fc2_b, out, out,
                                                                 LTOK, DIMC, HIDD);
}

// Round 14
// 317.635 us; speedup vs baseline: 1.2637x; 1.0679x over previous
//
#include <hip/hip_runtime.h>

// ---------- constants (problem is fixed-shape) ----------
#define LTOK 36864     // H*W = 192*192
#define DIMC 384
#define NHEADS 6
#define HDIM 64
#define HIDD 768
#define NWIN 12        // windows per side
#define WSZ 16
#define OWS 24
#define KVTOK 576      // 24*24

using bf16x8 = __attribute__((ext_vector_type(8))) short;
using f32x4  = __attribute__((ext_vector_type(4))) float;

__device__ inline unsigned short f2bf(float f) {
  unsigned u = __float_as_uint(f);
  return (unsigned short)((u + 0x7FFFu + ((u >> 16) & 1u)) >> 16);
}
__device__ inline float bf2f(unsigned short h) {
  return __uint_as_float(((unsigned)h) << 16);
}
__device__ __forceinline__ unsigned cvt_pk_bf16(float lo, float hi) {
  unsigned r;
  asm volatile("v_cvt_pk_bf16_f32 %0, %1, %2" : "=v"(r) : "v"(lo), "v"(hi));
  return r;
}
__device__ __forceinline__ unsigned short f2bf1(float x) {
  return (unsigned short)(cvt_pk_bf16(x, x) & 0xffffu);
}
__device__ __forceinline__ float fexp2(float x) {
#if __has_builtin(__builtin_amdgcn_exp2f)
  return __builtin_amdgcn_exp2f(x);
#else
  return exp2f(x);
#endif
}

typedef __attribute__((address_space(1))) const unsigned int GAS_U32;
typedef __attribute__((address_space(3))) unsigned int LAS_U32;
__device__ __forceinline__ void gl16(const void* g, void* l) {
  __builtin_amdgcn_global_load_lds((GAS_U32*)g, (LAS_U32*)l, 16, 0, 0);
}

// ---------- fused weight transposes: all 4 convt in one launch ----------
__global__ void prep_kernel(const float* __restrict__ qkv_w, const float* __restrict__ proj_w,
                            const float* __restrict__ fc1_w, const float* __restrict__ fc2_w,
                            unsigned short* __restrict__ wq, unsigned short* __restrict__ wp,
                            unsigned short* __restrict__ w1, unsigned short* __restrict__ w2) {
  int id = blockIdx.x * 256 + threadIdx.x;
  if (id < 442368) {                       // wq[n*384+k] = qkv_w[k*1152+n]
    int n = id / 384, k = id - n * 384;
    wq[id] = f2bf(qkv_w[(size_t)k * 1152 + n]);
  } else if (id < 589824) {                // wp
    int i = id - 442368;
    int n = i / 384, k = i - n * 384;
    wp[i] = f2bf(proj_w[(size_t)k * 384 + n]);
  } else if (id < 884736) {                // w1[n*384+k] = fc1_w[k*768+n]
    int i = id - 589824;
    int n = i / 384, k = i - n * 384;
    w1[i] = f2bf(fc1_w[(size_t)k * 768 + n]);
  } else {                                 // w2[n*768+k] = fc2_w[k*384+n]
    int i = id - 884736;
    int n = i / 768, k = i - n * 768;
    w2[i] = f2bf(fc2_w[(size_t)k * 384 + n]);
  }
}

// ---------- rel-pos bias expand (x8, f32): biasm8[head][q(256)][kt(576)] ----------
__global__ void rpb_expand_kernel(const float* __restrict__ rpb, float* __restrict__ biasm8) {
  int id = blockIdx.x * 256 + threadIdx.x;
  if (id >= NHEADS * 256 * 576) return;
  int head = id / 147456;
  int rem = id - head * 147456;
  int q = rem / 576;
  int kt = rem - q * 576;
  int ty = q >> 4, tx = q & 15;
  int oy = kt / 24, ox = kt - (kt / 24) * 24;
  biasm8[id] = rpb[((ty - oy + 23) * 39 + (tx - ox + 23)) * NHEADS + head] * 8.0f;
}

// ---------- LayerNorm: f32 or bf16 in -> bf16 out, one wave per row ----------
template <int BF16IN>
__global__ __launch_bounds__(256) void ln_kernel(const void* __restrict__ xv,
                                                 const float* __restrict__ g,
                                                 const float* __restrict__ b,
                                                 unsigned short* __restrict__ out) {
  int row = blockIdx.x * 4 + (threadIdx.x >> 6);
  int lane = threadIdx.x & 63;
  float v[6];
  float s = 0.f, ss = 0.f;
#pragma unroll
  for (int i = 0; i < 6; ++i) {
    int c = lane + i * 64;
    if (BF16IN) v[i] = bf2f(((const unsigned short*)xv)[(size_t)row * DIMC + c]);
    else        v[i] = ((const float*)xv)[(size_t)row * DIMC + c];
    s += v[i];
    ss += v[i] * v[i];
  }
#pragma unroll
  for (int off = 32; off; off >>= 1) {
    s += __shfl_xor(s, off);
    ss += __shfl_xor(ss, off);
  }
  float mean = s * (1.f / DIMC);
  float var = ss * (1.f / DIMC) - mean * mean;
  float rstd = rsqrtf(var + 1e-5f);
  unsigned short* outr = out + (size_t)row * DIMC;
#pragma unroll
  for (int i = 0; i < 6; ++i) {
    int c = lane + i * 64;
    outr[c] = f2bf((v[i] - mean) * rstd * g[c] + b[c]);
  }
}

// ---------- bf16 MFMA GEMM: BK=32, 3-buffer counted-vmcnt pipeline + XCD swizzle ----------
// EPI 0: bf16 = acc+bias            (qkv)
// EPI 2: bf16 = gelu(acc+bias)      (fc1)
// EPI 3: bf16 = f32resid+acc+bias   (proj -> xa bf16)
// EPI 4: f32  = bf16resid+acc+bias  (fc2 -> final out)
template <int EPI>
__global__ __launch_bounds__(256) void gemm_bf16(const unsigned short* __restrict__ A,
                                                 const unsigned short* __restrict__ Bt,
                                                 const float* __restrict__ bias,
                                                 const void* __restrict__ residv,
                                                 void* __restrict__ outv,
                                                 int M, int N, int K) {
  __shared__ unsigned short As[3][4096];  // 3 bufs x 8KB
  __shared__ unsigned short Bs[3][4096];
  const int tid = threadIdx.x;
  // bijective XCD swizzle (nwg % 8 == 0 for all our grids)
  int id = blockIdx.y * gridDim.x + blockIdx.x;
  int chunk = (gridDim.x * gridDim.y) >> 3;
  int lid = (id & 7) * chunk + (id >> 3);
  const int m0 = (lid / gridDim.x) * 128;
  const int n0 = (lid % gridDim.x) * 128;
  const int lane = tid & 63;
  const int wave = tid >> 6;
  const int wr = wave >> 1;
  const int wc = wave & 1;
  const int l15 = lane & 15, l4 = lane >> 4;

  f32x4 acc[4][4];
#pragma unroll
  for (int i = 0; i < 4; ++i)
#pragma unroll
    for (int j = 0; j < 4; ++j) acc[i][j] = (f32x4){0.f, 0.f, 0.f, 0.f};

  const int srow = tid >> 2;
  const int scol = (tid & 3) << 3;
  const unsigned short* ga = A + (size_t)(m0 + srow) * K + scol;
  const unsigned short* gb = Bt + (size_t)(n0 + srow) * K + scol;

#define STAGE(buf, k0)                                        \
  do {                                                        \
    unsigned short* lA = As[buf] + wave * 512;                \
    unsigned short* lB = Bs[buf] + wave * 512;                \
    gl16(ga + (k0), lA);                                      \
    gl16(ga + (size_t)64 * K + (k0), lA + 2048);              \
    gl16(gb + (k0), lB);                                      \
    gl16(gb + (size_t)64 * K + (k0), lB + 2048);              \
  } while (0)

  const int nt = K >> 5;
  STAGE(0, 0);
  STAGE(1, 32);   // 8 loads/thread outstanding

  for (int t = 0; t < nt; ++t) {
    const int cur = t % 3;
    if (t + 1 < nt) {
      asm volatile("s_waitcnt vmcnt(4)" ::: "memory");  // own buf[t] loads retired (in-order)
    } else {
      asm volatile("s_waitcnt vmcnt(0)" ::: "memory");  // tail: drain remaining stage
    }
    __builtin_amdgcn_s_barrier();                       // all waves' buf[t] complete

    if (t + 2 < nt) STAGE((t + 2) % 3, (t + 2) * 32);   // overwrites buf read in iter t-1: safe

    const unsigned short* arp = As[cur] + (wr * 64 + l15) * 32 + l4 * 8;
    const unsigned short* brp = Bs[cur] + (wc * 64 + l15) * 32 + l4 * 8;
    bf16x8 af[4], bfr[4];
#pragma unroll
    for (int i = 0; i < 4; ++i) af[i] = *(const bf16x8*)(arp + i * 512);
#pragma unroll
    for (int j = 0; j < 4; ++j) bfr[j] = *(const bf16x8*)(brp + j * 512);
#pragma unroll
    for (int i = 0; i < 4; ++i)
#pragma unroll
      for (int j = 0; j < 4; ++j)
        acc[i][j] = __builtin_amdgcn_mfma_f32_16x16x32_bf16(af[i], bfr[j], acc[i][j], 0, 0, 0);
  }
#undef STAGE

#pragma unroll
  for (int j = 0; j < 4; ++j) {
    int gcol = n0 + wc * 64 + j * 16 + l15;
    float bv = bias[gcol];
#pragma unroll
    for (int i = 0; i < 4; ++i) {
#pragma unroll
      for (int r = 0; r < 4; ++r) {
        int grow = m0 + wr * 64 + i * 16 + l4 * 4 + r;
        float v = acc[i][j][r] + bv;
        size_t idx = (size_t)grow * N + gcol;
        if (EPI == 0) {
          ((unsigned short*)outv)[idx] = f2bf(v);
        } else if (EPI == 2) {
          float gv = 0.5f * v * (1.f + erff(v * 0.70710678118654752f));
          ((unsigned short*)outv)[idx] = f2bf(gv);
        } else if (EPI == 3) {
          ((unsigned short*)outv)[idx] = f2bf(((const float*)residv)[idx] + v);
        } else {  // EPI 4
          ((float*)outv)[idx] = bf2f(((const unsigned short*)residv)[idx]) + v;
        }
      }
    }
  }
}

// ---------- MFMA flash attention (dbuf K/V^T, 1 barrier/tile, lsum via ones-MFMA) ----------
__global__ __launch_bounds__(256, 3) void attn_kernel(const unsigned short* __restrict__ qkv,
                                                      const float* __restrict__ biasm8,
                                                      unsigned short* __restrict__ att) {
  __shared__ unsigned short ks[2][64][72];   // K tile [kt][d], dbuf
  __shared__ unsigned short vts[2][64][72];  // V^T tile [d][kt], dbuf
  __shared__ unsigned short pt[4][32][40];   // per-wave P kk-half
  int bid = blockIdx.x;                       // 0..1727
  int lid = (bid & 7) * 216 + (bid >> 3);     // bijective XCD swizzle (1728 = 8*216)
  const int hw = lid >> 1;
  const int qh = lid & 1;
  const int win = hw / NHEADS;
  const int head = hw - win * NHEADS;
  const int wy = win / NWIN, wx = win - (win / NWIN) * NWIN;
  const int tid = threadIdx.x;
  const int w = tid >> 6, lane = tid & 63;
  const int l15 = lane & 15, l4 = lane >> 4;
  const float SC02 = 0.125f * 1.44269504f;
  const float C0 = -8.f * 1.44269504f;
  const bf16x8 ones = {(short)0x3F80, (short)0x3F80, (short)0x3F80, (short)0x3F80,
                       (short)0x3F80, (short)0x3F80, (short)0x3F80, (short)0x3F80};

  const int qrow0 = qh * 128 + w * 32;

  bf16x8 qf[2][2];
#pragma unroll
  for (int jq = 0; jq < 2; ++jq) {
    int q = qrow0 + jq * 16 + l15;
    int gy = wy * WSZ + (q >> 4), gx = wx * WSZ + (q & 15);
    const unsigned short* qp = qkv + (size_t)(gy * 192 + gx) * 1152 + head * HDIM + l4 * 8;
    qf[jq][0] = *(const bf16x8*)qp;
    qf[jq][1] = *(const bf16x8*)(qp + 32);
  }

  const float* bias_base = biasm8 + (size_t)head * 147456 + (size_t)(qrow0 + l15) * 576 + l4 * 4;

#define KS_W(buf, k0v, k1v)                          \
  do {                                               \
    *(uint4*)&ks[buf][lane][w * 16] = (k0v);         \
    *(uint4*)&ks[buf][lane][w * 16 + 8] = (k1v);     \
  } while (0)
#define VTS_W(buf, v0v, v1v)                                           \
  do {                                                                 \
    const unsigned short* vv = (const unsigned short*)&(v0v);          \
    _Pragma("unroll") for (int j = 0; j < 8; ++j)                      \
        vts[buf][w * 16 + j][lane] = vv[j];                            \
    vv = (const unsigned short*)&(v1v);                                \
    _Pragma("unroll") for (int j = 0; j < 8; ++j)                      \
        vts[buf][w * 16 + 8 + j][lane] = vv[j];                        \
  } while (0)

  {
    int kt = lane;
    int oy = kt / OWS, ox = kt - (kt / OWS) * OWS;
    int gy = wy * WSZ + oy - 4, gx = wx * WSZ + ox - 4;
    uint4 k0 = {0,0,0,0}, k1 = {0,0,0,0}, v0 = {0,0,0,0}, v1 = {0,0,0,0};
    if ((unsigned)gy < 192u && (unsigned)gx < 192u) {
      const unsigned short* gp = qkv + (size_t)(gy * 192 + gx) * 1152 + DIMC + head * HDIM + w * 16;
      k0 = *(const uint4*)gp;         k1 = *(const uint4*)(gp + 8);
      v0 = *(const uint4*)(gp + 384); v1 = *(const uint4*)(gp + 392);
    }
    KS_W(0, k0, k1);
    VTS_W(0, v0, v1);
  }

  f32x4 sacc[4][2];
#pragma unroll
  for (int i = 0; i < 4; ++i)
#pragma unroll
    for (int j2 = 0; j2 < 2; ++j2)
      sacc[i][j2] = *(const f32x4*)(bias_base + j2 * (16 * 576) + i * 16);

  __syncthreads();

  f32x4 oacc[2][4];
#pragma unroll
  for (int i = 0; i < 2; ++i)
#pragma unroll
    for (int j = 0; j < 4; ++j) oacc[i][j] = (f32x4){0.f, 0.f, 0.f, 0.f};
  f32x4 ol[2];  // row-sum accumulator: D layout gives lane its own 4 q-rows
  ol[0] = (f32x4){0.f, 0.f, 0.f, 0.f};
  ol[1] = (f32x4){0.f, 0.f, 0.f, 0.f};

  for (int kb = 0; kb < 9; ++kb) {
    const int cur = kb & 1;
    const bool have = kb < 8;
    uint4 pk0 = {0,0,0,0}, pk1 = {0,0,0,0}, pv0 = {0,0,0,0}, pv1 = {0,0,0,0};
    if (have) {
      int kt = (kb + 1) * 64 + lane;
      int oy = kt / OWS, ox = kt - (kt / OWS) * OWS;
      int gy = wy * WSZ + oy - 4, gx = wx * WSZ + ox - 4;
      if ((unsigned)gy < 192u && (unsigned)gx < 192u) {
        const unsigned short* gp = qkv + (size_t)(gy * 192 + gx) * 1152 + DIMC + head * HDIM + w * 16;
        pk0 = *(const uint4*)gp;         pk1 = *(const uint4*)(gp + 8);
        pv0 = *(const uint4*)(gp + 384); pv1 = *(const uint4*)(gp + 392);
      }
    }

#pragma unroll
    for (int kk = 0; kk < 2; ++kk) {
      bf16x8 kf[4];
#pragma unroll
      for (int i = 0; i < 4; ++i)
        kf[i] = *(const bf16x8*)&ks[cur][i * 16 + l15][kk * 32 + l4 * 8];
      __builtin_amdgcn_s_setprio(1);
#pragma unroll
      for (int i = 0; i < 4; ++i)
#pragma unroll
        for (int j2 = 0; j2 < 2; ++j2)
          sacc[i][j2] = __builtin_amdgcn_mfma_f32_16x16x32_bf16(kf[i], qf[j2][kk], sacc[i][j2], 0, 0, 0);
      __builtin_amdgcn_s_setprio(0);
    }

#pragma unroll
    for (int i = 0; i < 4; ++i)
#pragma unroll
      for (int j2 = 0; j2 < 2; ++j2)
#pragma unroll
        for (int r = 0; r < 4; ++r)
          sacc[i][j2][r] = fexp2(fmaf(sacc[i][j2][r], SC02, C0));

#pragma unroll
    for (int kk = 0; kk < 2; ++kk) {
#pragma unroll
      for (int i2 = 0; i2 < 2; ++i2)
#pragma unroll
        for (int j2 = 0; j2 < 2; ++j2) {
          int i = kk * 2 + i2;
          uint2 pk;
          pk.x = cvt_pk_bf16(sacc[i][j2][0], sacc[i][j2][1]);
          pk.y = cvt_pk_bf16(sacc[i][j2][2], sacc[i][j2][3]);
          *(uint2*)&pt[w][j2 * 16 + l15][i2 * 16 + l4 * 4] = pk;
        }
      bf16x8 pf[2], vf[4];
#pragma unroll
      for (int j2 = 0; j2 < 2; ++j2)
        pf[j2] = *(const bf16x8*)&pt[w][j2 * 16 + l15][l4 * 8];
#pragma unroll
      for (int jd = 0; jd < 4; ++jd)
        vf[jd] = *(const bf16x8*)&vts[cur][jd * 16 + l15][kk * 32 + l4 * 8];
      __builtin_amdgcn_s_setprio(1);
#pragma unroll
      for (int j2 = 0; j2 < 2; ++j2) {
#pragma unroll
        for (int jd = 0; jd < 4; ++jd)
          oacc[j2][jd] = __builtin_amdgcn_mfma_f32_16x16x32_bf16(pf[j2], vf[jd], oacc[j2][jd], 0, 0, 0);
        ol[j2] = __builtin_amdgcn_mfma_f32_16x16x32_bf16(pf[j2], ones, ol[j2], 0, 0, 0);
      }
      __builtin_amdgcn_s_setprio(0);
    }

    if (have) {
      KS_W(cur ^ 1, pk0, pk1);
      VTS_W(cur ^ 1, pv0, pv1);
      const float* bp = bias_base + (kb + 1) * 64;
#pragma unroll
      for (int i = 0; i < 4; ++i)
#pragma unroll
        for (int j2 = 0; j2 < 2; ++j2)
          sacc[i][j2] = *(const f32x4*)(bp + j2 * (16 * 576) + i * 16);
    }
    __syncthreads();
  }
#undef KS_W
#undef VTS_W

  // ----- epilogue: normalize + store (ol[j2][r] = lsum for q-row l4*4+r, no shfl) -----
#pragma unroll
  for (int j2 = 0; j2 < 2; ++j2) {
#pragma unroll
    for (int r = 0; r < 4; ++r) {
      float il = 1.f / ol[j2][r];
      int q = qrow0 + j2 * 16 + l4 * 4 + r;
      int gy = wy * WSZ + (q >> 4), gx = wx * WSZ + (q & 15);
      unsigned short* op = att + (size_t)(gy * 192 + gx) * DIMC + head * HDIM + l15;
#pragma unroll
      for (int jd = 0; jd < 4; ++jd) op[jd * 16] = f2bf1(oacc[j2][jd][r] * il);
    }
  }
}

// ---------- launch ----------
extern "C" void kernel_launch(void* const* d_in, const int* in_sizes, int n_in,
                              void* d_out, int out_size, void* d_ws, size_t ws_size,
                              hipStream_t stream) {
  const float* x      = (const float*)d_in[0];
  const float* n1g    = (const float*)d_in[1];
  const float* n1b    = (const float*)d_in[2];
  const float* qkv_w  = (const float*)d_in[3];
  const float* qkv_b  = (const float*)d_in[4];
  const float* rpb    = (const float*)d_in[5];
  const float* proj_w = (const float*)d_in[6];
  const float* proj_b = (const float*)d_in[7];
  const float* n2g    = (const float*)d_in[8];
  const float* n2b    = (const float*)d_in[9];
  const float* fc1_w  = (const float*)d_in[10];
  const float* fc1_b  = (const float*)d_in[11];
  const float* fc2_w  = (const float*)d_in[12];
  const float* fc2_b  = (const float*)d_in[13];
  float* out = (float*)d_out;

  char* ws = (char*)d_ws;
  unsigned short* xn   = (unsigned short*)ws;                           // L*384 bf16; reused as biasm8 (f32) during attn
  unsigned short* qkvb = (unsigned short*)(ws + 28311552);              // L*1152 bf16; first 56.6MB reused as h1
  unsigned short* xa   = (unsigned short*)(ws + 28311552 + 56623104);   // L*384 bf16 (upper qkvb, free after attn)
  unsigned short* att  = (unsigned short*)(ws + 28311552 + 84934656);   // L*384 bf16
  unsigned short* wq   = (unsigned short*)(ws + 141557760);             // 1152*384
  unsigned short* wp   = wq + 1152 * 384;                               // 384*384
  unsigned short* w1   = wp + 384 * 384;                                // 768*384
  unsigned short* w2   = w1 + 768 * 384;                                // 384*768
  float* biasm8 = (float*)ws;  // 884736 f32 = 3.54 MB; valid between qkv GEMM and LN2

  // fused weight transposes (1179648 elems)
  prep_kernel<<<4608, 256, 0, stream>>>(qkv_w, proj_w, fc1_w, fc2_w, wq, wp, w1, w2);

  // LN1 (f32 in)
  ln_kernel<0><<<LTOK / 4, 256, 0, stream>>>(x, n1g, n1b, xn);
  // qkv = xn @ qkv_w + b
  gemm_bf16<0><<<dim3(1152 / 128, LTOK / 128), 256, 0, stream>>>(xn, wq, qkv_b, nullptr, qkvb,
                                                                 LTOK, 1152, DIMC);
  // bias matrix expand (f32, x8) into xn region
  rpb_expand_kernel<<<(NHEADS * 256 * 576 + 255) / 256, 256, 0, stream>>>(rpb, biasm8);
  // attention
  attn_kernel<<<dim3(NHEADS * 144 * 2), 256, 0, stream>>>(qkvb, biasm8, att);
  // xa = bf16(x + att @ proj_w + b)   [EPI 3]
  gemm_bf16<3><<<dim3(DIMC / 128, LTOK / 128), 256, 0, stream>>>(att, wp, proj_b, x, xa,
                                                                 LTOK, DIMC, DIMC);
  // LN2 (bf16 in)
  ln_kernel<1><<<LTOK / 4, 256, 0, stream>>>(xa, n2g, n2b, xn);
  // h1 = gelu(xn @ fc1_w + b)
  gemm_bf16<2><<<dim3(HIDD / 128, LTOK / 128), 256, 0, stream>>>(xn, w1, fc1_b, nullptr, qkvb,
                                                                 LTOK, HIDD, DIMC);
  // out = f32(xa + h1 @ fc2_w + b)    [EPI 4]
  gemm_bf16<4><<<dim3(DIMC / 128, LTOK / 128), 256, 0, stream>>>(qkvb, w2, fc2_b, xa, out,
                                                                 LTOK, DIMC, HIDD);
}